// Round 1
// baseline (528.327 us; speedup 1.0000x reference)
//
#include <hip/hip_runtime.h>
#include <stdint.h>

#define NB 4
#define KTOT 5480
#define PER_IMG 258720
#define SCORE_THR 0.02f
#define IOU_THR 0.45f

__constant__ int cFEAT[6]    = {20,10,5,3,2,1};
__constant__ int cSTRIDE[6]  = {16,32,64,107,160,320};
__constant__ int cMIN[6]     = {48,100,150,202,253,304};
__constant__ int cMAX[6]     = {100,150,202,253,304,320};
__constant__ int cNFLAT[6]   = {192000,48000,12000,4320,1920,480};
__constant__ int cFLATOFF[6] = {0,192000,240000,252000,256320,258240};
__constant__ int cKSEL[6]    = {1000,1000,1000,1000,1000,480};
__constant__ int cKOFF[6]    = {0,1000,2000,3000,4000,5000};
__constant__ int cROWCUM[7]  = {0,2400,3000,3150,3204,3228,3234};
__constant__ double cRATIO[6] = {1.0,1.0,0.5,2.0,1.0/3.0,3.0};

// ---------------- K1: softmax over 81 classes, masked flat scores ----------------
__global__ __launch_bounds__(256) void k_softmax(
    const float* __restrict__ c0, const float* __restrict__ c1,
    const float* __restrict__ c2, const float* __restrict__ c3,
    const float* __restrict__ c4, const float* __restrict__ c5,
    float* __restrict__ scores)
{
  int w = (int)((blockIdx.x * blockDim.x + threadIdx.x) >> 6);
  int lane = threadIdx.x & 63;
  if (w >= NB * 3234) return;
  int b = w / 3234, rg = w % 3234;
  int lev = 0;
  #pragma unroll
  for (int l = 0; l < 5; ++l) lev += (rg >= cROWCUM[l + 1]);
  int row = rg - cROWCUM[lev];
  const float* cls = (lev==0)?c0:(lev==1)?c1:(lev==2)?c2:(lev==3)?c3:(lev==4)?c4:c5;
  int f = cFEAT[lev], ff = f * f;
  int a = row % 6, cell = row / 6;
  int x = cell % f, y = cell / f;
  const float* pc = cls + (size_t)(b * 486 + a * 81) * ff + y * f + x;
  float v1 = pc[lane * ff];
  float v2 = (lane <= 16) ? pc[(lane + 64) * ff] : __uint_as_float(0xff800000u);
  float mx = fmaxf(v1, v2);
  #pragma unroll
  for (int m = 32; m; m >>= 1) mx = fmaxf(mx, __shfl_xor(mx, m));
  float e1 = expf(v1 - mx);
  float e2 = (lane <= 16) ? expf(v2 - mx) : 0.f;
  float sm = e1 + e2;
  #pragma unroll
  for (int m = 32; m; m >>= 1) sm += __shfl_xor(sm, m);
  float* out = scores + (size_t)b * PER_IMG + cFLATOFF[lev] + row * 80;
  float p1 = e1 / sm;
  out[lane] = (p1 > SCORE_THR) ? p1 : -1.f;
  if (lane < 16) { float p2 = e2 / sm; out[lane + 64] = (p2 > SCORE_THR) ? p2 : -1.f; }
}

// ---------------- K2: per (image, level) exact top-k selection --------------------
// sortkey: (valbits << 21) | (0x1FFFFF ^ (lev<<18 | flat_idx)); valbits=0 for invalid.
__global__ __launch_bounds__(1024) void k_topk(
    const float* __restrict__ scores, unsigned long long* __restrict__ selkeys)
{
  int b = blockIdx.x / 6, lev = blockIdx.x % 6;
  int n = cNFLAT[lev], k = cKSEL[lev];
  const float* s = scores + (size_t)b * PER_IMG + cFLATOFF[lev];
  unsigned long long* out = selkeys + (size_t)b * KTOT + cKOFF[lev];
  int tid = threadIdx.x;

  __shared__ unsigned hist[256];
  __shared__ unsigned sh_cnt, sh_eq, sh_byte, sh_r;
  __shared__ unsigned eqbuf[1024];
  __shared__ unsigned scanbuf[1024];

  unsigned levtag = (unsigned)lev << 18;

  if (k == n) {  // select everything (level 5)
    for (int i = tid; i < n; i += 1024) {
      float v = s[i];
      unsigned kb = (v > SCORE_THR) ? __float_as_uint(v) : 0u;
      out[i] = ((unsigned long long)kb << 21) |
               (unsigned long long)(0x1FFFFFu ^ (levtag | (unsigned)i));
    }
    return;
  }

  if (tid == 0) sh_cnt = 0;
  __syncthreads();
  {
    unsigned lc = 0;
    for (int i = tid; i < n; i += 1024) lc += (s[i] > SCORE_THR);
    atomicAdd(&sh_cnt, lc);
  }
  __syncthreads();
  unsigned c = sh_cnt;
  __syncthreads();

  if (c >= (unsigned)k) {
    // radix-select the k-th largest value key
    unsigned prefix = 0, r = (unsigned)k;
    for (int pass = 3; pass >= 0; --pass) {
      int shift = pass * 8;
      for (int i = tid; i < 256; i += 1024) hist[i] = 0;
      __syncthreads();
      for (int i = tid; i < n; i += 1024) {
        float v = s[i];
        unsigned kb = (v > SCORE_THR) ? __float_as_uint(v) : 0u;
        bool match = (pass == 3) || (((kb ^ prefix) >> (shift + 8)) == 0u);
        if (match) atomicAdd(&hist[(kb >> shift) & 255u], 1u);
      }
      __syncthreads();
      if (tid == 0) {
        unsigned cum = 0, byte = 0, rr = r;
        for (int bb = 255; bb >= 0; --bb) {
          unsigned h = hist[bb];
          if (cum + h >= r) { byte = (unsigned)bb; rr = r - cum; break; }
          cum += h;
        }
        sh_byte = byte; sh_r = rr;
      }
      __syncthreads();
      prefix |= (sh_byte << shift);
      r = sh_r;
      __syncthreads();
    }
    unsigned Kstar = prefix;
    if (tid == 0) { sh_cnt = 0; sh_eq = 0; }
    __syncthreads();
    for (int i = tid; i < n; i += 1024) {
      float v = s[i];
      unsigned kb = (v > SCORE_THR) ? __float_as_uint(v) : 0u;
      if (kb > Kstar) {
        unsigned slot = atomicAdd(&sh_cnt, 1u);
        out[slot] = ((unsigned long long)kb << 21) |
                    (unsigned long long)(0x1FFFFFu ^ (levtag | (unsigned)i));
      } else if (kb == Kstar) {
        unsigned es = atomicAdd(&sh_eq, 1u);
        if (es < 1024u) eqbuf[es] = (unsigned)i;
      }
    }
    __syncthreads();
    unsigned m = sh_cnt;
    unsigned e = (sh_eq < 1024u) ? sh_eq : 1024u;
    unsigned need = (unsigned)k - m;  // r >= 1
    if (e > need) {
      // sort equal-key indices ascending, keep smallest `need`
      if ((unsigned)tid >= e) eqbuf[tid] = 0xFFFFFFFFu;
      __syncthreads();
      for (unsigned sz = 2; sz <= 1024; sz <<= 1)
        for (unsigned st = sz >> 1; st; st >>= 1) {
          unsigned i = (unsigned)tid;
          unsigned l = i ^ st;
          if (l > i) {
            bool up = ((i & sz) == 0);
            unsigned A = eqbuf[i], Bv = eqbuf[l];
            if ((A > Bv) == up) { eqbuf[i] = Bv; eqbuf[l] = A; }
          }
          __syncthreads();
        }
    }
    __syncthreads();
    if (tid < (int)need)
      out[m + tid] = ((unsigned long long)Kstar << 21) |
                     (unsigned long long)(0x1FFFFFu ^ (levtag | eqbuf[tid]));
  } else {
    // fewer candidates than k: all candidates + (k-c) smallest-index fillers
    if (tid == 0) sh_cnt = 0;
    __syncthreads();
    for (int i = tid; i < n; i += 1024) {
      float v = s[i];
      if (v > SCORE_THR) {
        unsigned slot = atomicAdd(&sh_cnt, 1u);
        out[slot] = ((unsigned long long)__float_as_uint(v) << 21) |
                    (unsigned long long)(0x1FFFFFu ^ (levtag | (unsigned)i));
      }
    }
    __syncthreads();
    unsigned need = (unsigned)k - c;
    unsigned base = 0;
    for (int start = 0; start < n && base < need; start += 1024) {
      int i = start + tid;
      unsigned pred = (i < n && !(s[i] > SCORE_THR)) ? 1u : 0u;
      scanbuf[tid] = pred;
      __syncthreads();
      for (int off = 1; off < 1024; off <<= 1) {
        unsigned add = (tid >= off) ? scanbuf[tid - off] : 0u;
        unsigned v = scanbuf[tid];
        __syncthreads();
        scanbuf[tid] = v + add;
        __syncthreads();
      }
      unsigned incl = scanbuf[tid];
      unsigned total = scanbuf[1023];
      unsigned excl = incl - pred;
      if (pred && (base + excl) < need)
        out[c + base + excl] =
            (unsigned long long)(0x1FFFFFu ^ (levtag | (unsigned)i));
      __syncthreads();
      base += total;
    }
  }
}

// ---------------- K3: per-image global sort (bitonic, LDS) + decode ---------------
__global__ __launch_bounds__(1024) void k_sortdec(
    const unsigned long long* __restrict__ selkeys,
    const float* __restrict__ g0, const float* __restrict__ g1,
    const float* __restrict__ g2, const float* __restrict__ g3,
    const float* __restrict__ g4, const float* __restrict__ g5,
    float* __restrict__ boxes, float* __restrict__ oscore,
    int* __restrict__ olabel, int* __restrict__ ovalid,
    int* __restrict__ okeep, float* __restrict__ obmax)
{
  int b = blockIdx.x;
  int tid = threadIdx.x;
  __shared__ unsigned long long keys[8192];
  __shared__ double ba[6][6][4];
  __shared__ float red[1024];
  if (tid < 36) {  // base anchors in f64, matching numpy
    int lev = tid / 6, a = tid % 6;
    double base = (double)cMIN[lev];
    double scl = (a == 1) ? sqrt((double)cMAX[lev] / (double)cMIN[lev]) : 1.0;
    double hr = sqrt(cRATIO[a]);
    double wr = 1.0 / hr;
    double wsz = base * scl * wr;
    double hsz = base * scl * hr;
    double cc = (double)cSTRIDE[lev] / 2.0;
    ba[lev][a][0] = cc - 0.5 * wsz;
    ba[lev][a][1] = cc - 0.5 * hsz;
    ba[lev][a][2] = cc + 0.5 * wsz;
    ba[lev][a][3] = cc + 0.5 * hsz;
  }
  for (int i = tid; i < 8192; i += 1024)
    keys[i] = (i < KTOT) ? selkeys[(size_t)b * KTOT + i] : 0ull;
  __syncthreads();
  // bitonic sort, descending
  for (unsigned sz = 2; sz <= 8192; sz <<= 1)
    for (unsigned st = sz >> 1; st; st >>= 1) {
      for (unsigned i = tid; i < 8192; i += 1024) {
        unsigned l = i ^ st;
        if (l > i) {
          bool up = ((i & sz) == 0);
          unsigned long long A = keys[i], Bv = keys[l];
          if ((A < Bv) == up) { keys[i] = Bv; keys[l] = A; }
        }
      }
      __syncthreads();
    }
  float lmax = 0.f;
  for (int p = tid; p < KTOT; p += 1024) {
    unsigned long long key = keys[p];
    unsigned tag = 0x1FFFFFu ^ (unsigned)(key & 0x1FFFFFull);
    int lev = tag >> 18;
    int fi = tag & 0x3FFFF;
    unsigned vb = (unsigned)(key >> 21);
    int valid = (vb != 0u);
    float score = valid ? __uint_as_float(vb) : 0.f;
    int label = fi % 80;
    int arow = fi / 80;
    int a = arow % 6, cell = arow / 6;
    int f = cFEAT[lev], ff = f * f;
    int x = cell % f, y = cell / f;
    const float* gb = (lev==0)?g0:(lev==1)?g1:(lev==2)?g2:(lev==3)?g3:(lev==4)?g4:g5;
    const float* pb = gb + (size_t)(b * 24 + a * 4) * ff + y * f + x;
    float d0 = pb[0] * 0.1f, d1 = pb[ff] * 0.1f;
    float d2 = pb[2 * ff] * 0.2f, d3 = pb[3 * ff] * 0.2f;
    const float MR = (float)4.135166556742356;
    d2 = fminf(fmaxf(d2, -MR), MR);
    d3 = fminf(fmaxf(d3, -MR), MR);
    double shx = (double)(x * cSTRIDE[lev]);
    double shy = (double)(y * cSTRIDE[lev]);
    float p0 = (float)(ba[lev][a][0] + shx);
    float p1 = (float)(ba[lev][a][1] + shy);
    float p2 = (float)(ba[lev][a][2] + shx);
    float p3 = (float)(ba[lev][a][3] + shy);
    float pxc = (p0 + p2) * 0.5f, pyc = (p1 + p3) * 0.5f;
    float pw = p2 - p0, ph = p3 - p1;
    float gx = pxc + pw * d0, gy = pyc + ph * d1;
    float gw = pw * expf(d2), gh = ph * expf(d3);
    float x1 = gx - 0.5f * gw, y1 = gy - 0.5f * gh;
    float x2 = gx + 0.5f * gw, y2 = gy + 0.5f * gh;
    x1 = fminf(fmaxf(x1, 0.f), 320.f);
    y1 = fminf(fmaxf(y1, 0.f), 320.f);
    x2 = fminf(fmaxf(x2, 0.f), 320.f);
    y2 = fminf(fmaxf(y2, 0.f), 320.f);
    size_t o = (size_t)(b * KTOT + p);
    boxes[o * 4 + 0] = x1; boxes[o * 4 + 1] = y1;
    boxes[o * 4 + 2] = x2; boxes[o * 4 + 3] = y2;
    oscore[o] = score; olabel[o] = label; ovalid[o] = valid; okeep[o] = 0;
    lmax = fmaxf(lmax, fmaxf(fmaxf(x1, y1), fmaxf(x2, y2)));
  }
  red[tid] = lmax;
  __syncthreads();
  for (int s2 = 512; s2; s2 >>= 1) {
    if (tid < s2) red[tid] = fmaxf(red[tid], red[tid + s2]);
    __syncthreads();
  }
  if (tid == 0) obmax[b] = red[0];
}

// ---------------- K4: per (image,class) greedy NMS, one wave each -----------------
__global__ __launch_bounds__(256) void k_nms(
    const float* __restrict__ boxes, const int* __restrict__ olabel,
    const int* __restrict__ ovalid, int* __restrict__ okeep,
    const float* __restrict__ obmax)
{
  int wv = blockIdx.x * 4 + (threadIdx.x >> 6);
  int lane = threadIdx.x & 63;
  int b = wv / 80, cls = wv % 80;
  __shared__ unsigned short lists[4][512];
  unsigned short* list = lists[threadIdx.x >> 6];
  const int* lab = olabel + b * KTOT;
  const int* val = ovalid + b * KTOT;
  float ofs = (float)cls * (obmax[b] + 1.0f);  // replicate reference offset exactly
  int nlist = 0;
  for (int base = 0; base < KTOT; base += 64) {
    int i = base + lane;
    bool pred = (i < KTOT) && (val[i] != 0) && (lab[i] == cls);
    unsigned long long ball = __ballot(pred);
    if (pred) {
      int pos = nlist + (int)__popcll(ball & ((1ull << lane) - 1ull));
      if (pos < 512) list[pos] = (unsigned short)i;
    }
    nlist += (int)__popcll(ball);
  }
  if (nlist > 512) nlist = 512;
  int S = (nlist + 63) >> 6;
  float x1[8], y1[8], x2[8], y2[8], ar[8];
  int alive[8];
  #pragma unroll
  for (int s = 0; s < 8; ++s) {
    x1[s] = y1[s] = x2[s] = y2[s] = ar[s] = 0.f; alive[s] = 0;
    int idx = s * 64 + lane;
    if (s < S && idx < nlist) {
      const float* bp = boxes + (size_t)(b * KTOT + list[idx]) * 4;
      x1[s] = bp[0] + ofs; y1[s] = bp[1] + ofs;
      x2[s] = bp[2] + ofs; y2[s] = bp[3] + ofs;
      ar[s] = (x2[s] - x1[s]) * (y2[s] - y1[s]);
      alive[s] = 1;
    }
  }
  #pragma unroll
  for (int s = 0; s < 8; ++s) {
    if (s < S) {
      int lim = nlist - s * 64; if (lim > 64) lim = 64;
      for (int li = 0; li < lim; ++li) {
        int i = s * 64 + li;
        int av = __shfl(alive[s], li);
        if (av) {
          float bx1 = __shfl(x1[s], li), by1 = __shfl(y1[s], li);
          float bx2 = __shfl(x2[s], li), by2 = __shfl(y2[s], li);
          float bar = __shfl(ar[s], li);
          #pragma unroll
          for (int t = 0; t < 8; ++t) {
            if (t < S) {
              float ix1 = fmaxf(x1[t], bx1), iy1 = fmaxf(y1[t], by1);
              float ix2 = fminf(x2[t], bx2), iy2 = fminf(y2[t], by2);
              float iw = fmaxf(ix2 - ix1, 0.f), ih = fmaxf(iy2 - iy1, 0.f);
              float inter = iw * ih;
              float iou = inter / (ar[t] + bar - inter);
              if ((iou > IOU_THR) && ((t * 64 + lane) > i)) alive[t] = 0;
            }
          }
        }
      }
    }
  }
  #pragma unroll
  for (int s = 0; s < 8; ++s) {
    int idx = s * 64 + lane;
    if (s < S && idx < nlist) okeep[b * KTOT + list[idx]] = alive[s];
  }
}

// ---------------- K5: final outputs ----------------------------------------------
__global__ __launch_bounds__(256) void k_write(
    const float* __restrict__ boxes, const float* __restrict__ oscore,
    const int* __restrict__ olabel, const int* __restrict__ okeep,
    float* __restrict__ out)
{
  int t = blockIdx.x * 256 + threadIdx.x;
  if (t >= NB * KTOT) return;
  float kf = okeep[t] ? 1.f : 0.f;
  const float* bp = boxes + (size_t)t * 4;
  float* det = out + (size_t)t * 5;
  det[0] = bp[0] * kf; det[1] = bp[1] * kf;
  det[2] = bp[2] * kf; det[3] = bp[3] * kf;
  det[4] = oscore[t] * kf;
  out[(size_t)NB * KTOT * 5 + t] = (float)olabel[t];
  out[(size_t)NB * KTOT * 6 + t] = kf;
}

extern "C" void kernel_launch(void* const* d_in, const int* in_sizes, int n_in,
                              void* d_out, int out_size, void* d_ws, size_t ws_size,
                              hipStream_t stream) {
  (void)in_sizes; (void)n_in; (void)out_size; (void)ws_size;
  // setup_inputs order: cls0, bb0, cls1, bb1, ...
  const float* cls[6]; const float* bbx[6];
  for (int i = 0; i < 6; ++i) {
    cls[i] = (const float*)d_in[2 * i];
    bbx[i] = (const float*)d_in[2 * i + 1];
  }
  char* ws = (char*)d_ws;
  float* scores = (float*)ws;                                         // 4,139,520 B
  unsigned long long* selkeys = (unsigned long long*)(ws + 4139520);  //   175,360 B
  float* boxes  = (float*)(ws + 4314880);                             //   350,720 B
  float* oscore = (float*)(ws + 4665600);                             //    87,680 B
  int*   olabel = (int*)(ws + 4753280);                               //    87,680 B
  int*   ovalid = (int*)(ws + 4840960);                               //    87,680 B
  int*   okeep  = (int*)(ws + 4928640);                               //    87,680 B
  float* obmax  = (float*)(ws + 5016320);                             //        16 B

  k_softmax<<<3234, 256, 0, stream>>>(cls[0], cls[1], cls[2], cls[3], cls[4], cls[5], scores);
  k_topk<<<24, 1024, 0, stream>>>(scores, selkeys);
  k_sortdec<<<4, 1024, 0, stream>>>(selkeys, bbx[0], bbx[1], bbx[2], bbx[3], bbx[4], bbx[5],
                                    boxes, oscore, olabel, ovalid, okeep, obmax);
  k_nms<<<80, 256, 0, stream>>>(boxes, olabel, ovalid, okeep, obmax);
  k_write<<<(NB * KTOT + 255) / 256, 256, 0, stream>>>(boxes, oscore, olabel, okeep, (float*)d_out);
}

// Round 2
// 279.530 us; speedup vs baseline: 1.8901x; 1.8901x over previous
//
#include <hip/hip_runtime.h>
#include <stdint.h>

#define NB 4
#define KTOT 5480
#define PER_IMG 258720
#define SCORE_THR 0.02f
#define IOU_THR 0.45f
#define REL_BASE 0x3CA3D70Bu   // smallest float bits > 0.02f

__constant__ int cFEAT[6]    = {20,10,5,3,2,1};
__constant__ int cSTRIDE[6]  = {16,32,64,107,160,320};
__constant__ int cMIN[6]     = {48,100,150,202,253,304};
__constant__ int cMAX[6]     = {100,150,202,253,304,320};
__constant__ int cNFLAT[6]   = {192000,48000,12000,4320,1920,480};
__constant__ int cFLATOFF[6] = {0,192000,240000,252000,256320,258240};
__constant__ int cKSEL[6]    = {1000,1000,1000,1000,1000,480};
__constant__ int cKOFF[6]    = {0,1000,2000,3000,4000,5000};
__constant__ int cROWCUM[7]  = {0,2400,3000,3150,3204,3228,3234};
__constant__ double cRATIO[6] = {1.0,1.0,0.5,2.0,1.0/3.0,3.0};

__device__ __forceinline__ unsigned long long mk_key(unsigned kb, int lev, unsigned idx) {
  return ((unsigned long long)kb << 21) |
         (unsigned long long)(0x1FFFFFu ^ (((unsigned)lev << 18) | idx));
}

// ---------------- K1: softmax over 81 classes + fused 13-bit histogram -----------
__global__ __launch_bounds__(256) void k_softmax(
    const float* __restrict__ c0, const float* __restrict__ c1,
    const float* __restrict__ c2, const float* __restrict__ c3,
    const float* __restrict__ c4, const float* __restrict__ c5,
    float* __restrict__ scores, unsigned* __restrict__ ghist)
{
  int w = (int)((blockIdx.x * blockDim.x + threadIdx.x) >> 6);
  int lane = threadIdx.x & 63;
  if (w >= NB * 3234) return;
  int b = w / 3234, rg = w % 3234;
  int lev = 0;
  #pragma unroll
  for (int l = 0; l < 5; ++l) lev += (rg >= cROWCUM[l + 1]);
  int row = rg - cROWCUM[lev];
  const float* cls = (lev==0)?c0:(lev==1)?c1:(lev==2)?c2:(lev==3)?c3:(lev==4)?c4:c5;
  int f = cFEAT[lev], ff = f * f;
  int a = row % 6, cell = row / 6;
  int x = cell % f, y = cell / f;
  const float* pc = cls + (size_t)(b * 486 + a * 81) * ff + y * f + x;
  float v1 = pc[lane * ff];
  float v2 = (lane <= 16) ? pc[(lane + 64) * ff] : __uint_as_float(0xff800000u);
  float mx = fmaxf(v1, v2);
  #pragma unroll
  for (int m = 32; m; m >>= 1) mx = fmaxf(mx, __shfl_xor(mx, m));
  float e1 = expf(v1 - mx);
  float e2 = (lane <= 16) ? expf(v2 - mx) : 0.f;
  float sm = e1 + e2;
  #pragma unroll
  for (int m = 32; m; m >>= 1) sm += __shfl_xor(sm, m);
  float* out = scores + (size_t)b * PER_IMG + cFLATOFF[lev] + row * 80;
  unsigned* h = ghist + (size_t)(b * 6 + lev) * 8192;
  float p1 = e1 / sm;
  out[lane] = (p1 > SCORE_THR) ? p1 : -1.f;
  if (p1 > SCORE_THR)
    atomicAdd(&h[(__float_as_uint(p1) - REL_BASE) >> 13], 1u);
  if (lane < 16) {
    float p2 = e2 / sm;
    out[lane + 64] = (p2 > SCORE_THR) ? p2 : -1.f;
    if (p2 > SCORE_THR)
      atomicAdd(&h[(__float_as_uint(p2) - REL_BASE) >> 13], 1u);
  }
}

// ---------------- K2a: find cutoff bin per (img,level) ---------------------------
// ctrl[task*8 + {0:mode,1:b1,2:m1,3:cnt,4:eq}]; mode 0=radix,1=filler,2=all
__global__ __launch_bounds__(1024) void k_cutoff(
    const unsigned* __restrict__ ghist, unsigned* __restrict__ ctrl)
{
  int task = blockIdx.x;
  int lev = task % 6;
  int tid = threadIdx.x;
  if (lev == 5) { if (tid == 0) ctrl[task * 8] = 2u; return; }
  unsigned k = (unsigned)cKSEL[lev];
  const unsigned* h = ghist + (size_t)task * 8192;
  unsigned loc[8];
  unsigned s = 0;
  #pragma unroll
  for (int j = 0; j < 8; ++j) { loc[j] = h[tid * 8 + j]; s += loc[j]; }
  __shared__ unsigned sc[1024];
  sc[tid] = s;
  __syncthreads();
  // suffix-inclusive sum: sc[t] = sum over t' >= t
  for (int off = 1; off < 1024; off <<= 1) {
    unsigned cur = sc[tid];
    unsigned add = (tid + off < 1024) ? sc[tid + off] : 0u;
    __syncthreads();
    sc[tid] = cur + add;
    __syncthreads();
  }
  unsigned c = sc[0];
  if (c < k) { if (tid == 0) ctrl[task * 8] = 1u; return; }
  unsigned above = (tid == 1023) ? 0u : sc[tid + 1];
  unsigned run = above;
  #pragma unroll
  for (int j = 7; j >= 0; --j) {
    unsigned hj = loc[j];
    if (run < k && run + hj >= k) {
      ctrl[task * 8 + 0] = 0u;
      ctrl[task * 8 + 1] = (unsigned)(tid * 8 + j);
      ctrl[task * 8 + 2] = run;  // m1
    }
    run += hj;
  }
}

// ---------------- K2b: grid-wide emit --------------------------------------------
__global__ __launch_bounds__(256) void k_emit(
    const float* __restrict__ scores, unsigned* __restrict__ ctrl,
    unsigned long long* __restrict__ selkeys, unsigned long long* __restrict__ eqbuf)
{
  int t = blockIdx.x * 256 + threadIdx.x;
  if (t >= NB * PER_IMG) return;
  int b = t / PER_IMG, r = t % PER_IMG;
  int lev = 0;
  #pragma unroll
  for (int l = 0; l < 5; ++l) lev += (r >= cFLATOFF[l + 1]);
  unsigned idx = (unsigned)(r - cFLATOFF[lev]);
  int task = b * 6 + lev;
  unsigned mode = ctrl[task * 8];
  float v = scores[t];
  unsigned long long* out = selkeys + (size_t)b * KTOT + cKOFF[lev];
  if (mode == 2u) {  // level 5: keep all
    unsigned kb = (v > SCORE_THR) ? __float_as_uint(v) : 0u;
    out[idx] = mk_key(kb, lev, idx);
    return;
  }
  if (mode != 0u) return;      // filler: handled in finalize
  if (!(v > SCORE_THR)) return;
  unsigned kb = __float_as_uint(v);
  unsigned d1 = (kb - REL_BASE) >> 13;
  unsigned b1 = ctrl[task * 8 + 1];
  if (d1 > b1) {
    unsigned slot = atomicAdd(&ctrl[task * 8 + 3], 1u);
    out[slot] = mk_key(kb, lev, idx);
  } else if (d1 == b1) {
    unsigned p = atomicAdd(&ctrl[task * 8 + 4], 1u);
    if (p < 4096u) eqbuf[(size_t)task * 4096 + p] = mk_key(kb, lev, idx);
  }
}

// ---------------- K2c: finalize (cutoff-bin ties, filler fallback) ---------------
__global__ __launch_bounds__(1024) void k_finalize(
    const float* __restrict__ scores, unsigned* __restrict__ ctrl,
    unsigned long long* __restrict__ selkeys, const unsigned long long* __restrict__ eqbuf)
{
  int task = blockIdx.x;
  int b = task / 6, lev = task % 6;
  int tid = threadIdx.x;
  unsigned mode = ctrl[task * 8];
  if (mode == 2u) return;
  unsigned k = (unsigned)cKSEL[lev];
  int n = cNFLAT[lev];
  unsigned long long* out = selkeys + (size_t)b * KTOT + cKOFF[lev];
  const unsigned long long* eq = eqbuf + (size_t)task * 4096;

  __shared__ unsigned long long sb[4096];
  __shared__ unsigned scanbuf[1024];
  __shared__ unsigned hist[256];
  __shared__ unsigned sh_cnt, sh_eq, sh_byte, sh_r;

  if (mode == 0u) {
    unsigned cnt = ctrl[task * 8 + 3];
    unsigned e = ctrl[task * 8 + 4];
    unsigned need = k - cnt;
    if (e <= 4096u) {
      if (e == need) {
        for (unsigned t = tid; t < need; t += 1024) out[cnt + t] = eq[t];
        return;
      }
      unsigned P = 1; while (P < e) P <<= 1;
      for (unsigned t = tid; t < P; t += 1024) sb[t] = (t < e) ? eq[t] : 0ull;
      __syncthreads();
      for (unsigned sz = 2; sz <= P; sz <<= 1)
        for (unsigned st = sz >> 1; st; st >>= 1) {
          for (unsigned w = tid; w < P / 2; w += 1024) {
            unsigned i = ((w & ~(st - 1)) << 1) | (w & (st - 1));
            unsigned l = i | st;
            bool up = ((i & sz) == 0);
            unsigned long long A = sb[i], B = sb[l];
            if ((A < B) == up) { sb[i] = B; sb[l] = A; }  // descending
          }
          __syncthreads();
        }
      for (unsigned t = tid; t < need; t += 1024) out[cnt + t] = sb[t];
      return;
    }
    // eq overflow (pathological): fall through to full slowpath re-emit
  }

  // ---------- slowpath: exact single-block selection (proven round-1 code) -------
  const float* s = scores + (size_t)b * PER_IMG + cFLATOFF[lev];
  unsigned levtag = (unsigned)lev << 18;
  unsigned* equ = (unsigned*)sb;  // u32 index buffer, cap 4096

  if (tid == 0) sh_cnt = 0;
  __syncthreads();
  {
    unsigned lc = 0;
    for (int i = tid; i < n; i += 1024) lc += (s[i] > SCORE_THR);
    atomicAdd(&sh_cnt, lc);
  }
  __syncthreads();
  unsigned c = sh_cnt;
  __syncthreads();

  if (c >= k) {
    unsigned prefix = 0, r = k;
    for (int pass = 3; pass >= 0; --pass) {
      int shift = pass * 8;
      for (int i = tid; i < 256; i += 1024) hist[i] = 0;
      __syncthreads();
      for (int i = tid; i < n; i += 1024) {
        float v = s[i];
        unsigned kb = (v > SCORE_THR) ? __float_as_uint(v) : 0u;
        bool match = (pass == 3) || (((kb ^ prefix) >> (shift + 8)) == 0u);
        if (match) atomicAdd(&hist[(kb >> shift) & 255u], 1u);
      }
      __syncthreads();
      if (tid == 0) {
        unsigned cum = 0, byte = 0, rr = r;
        for (int bb = 255; bb >= 0; --bb) {
          unsigned h = hist[bb];
          if (cum + h >= r) { byte = (unsigned)bb; rr = r - cum; break; }
          cum += h;
        }
        sh_byte = byte; sh_r = rr;
      }
      __syncthreads();
      prefix |= (sh_byte << shift);
      r = sh_r;
      __syncthreads();
    }
    unsigned Kstar = prefix;
    if (tid == 0) { sh_cnt = 0; sh_eq = 0; }
    __syncthreads();
    for (int i = tid; i < n; i += 1024) {
      float v = s[i];
      unsigned kb = (v > SCORE_THR) ? __float_as_uint(v) : 0u;
      if (kb > Kstar) {
        unsigned slot = atomicAdd(&sh_cnt, 1u);
        out[slot] = ((unsigned long long)kb << 21) |
                    (unsigned long long)(0x1FFFFFu ^ (levtag | (unsigned)i));
      } else if (kb == Kstar) {
        unsigned es = atomicAdd(&sh_eq, 1u);
        if (es < 4096u) equ[es] = (unsigned)i;
      }
    }
    __syncthreads();
    unsigned m = sh_cnt;
    unsigned e2 = (sh_eq < 4096u) ? sh_eq : 4096u;
    unsigned need = k - m;
    if (e2 > need) {
      unsigned P = 1; while (P < e2) P <<= 1;
      for (unsigned t = tid; t < P; t += 1024) if (t >= e2) equ[t] = 0xFFFFFFFFu;
      __syncthreads();
      for (unsigned sz = 2; sz <= P; sz <<= 1)
        for (unsigned st = sz >> 1; st; st >>= 1) {
          for (unsigned w = tid; w < P / 2; w += 1024) {
            unsigned i = ((w & ~(st - 1)) << 1) | (w & (st - 1));
            unsigned l = i | st;
            bool up = ((i & sz) == 0);
            unsigned A = equ[i], B = equ[l];
            if ((A > B) == up) { equ[i] = B; equ[l] = A; }  // ascending
          }
          __syncthreads();
        }
    }
    __syncthreads();
    for (unsigned t = tid; t < need; t += 1024)
      out[m + t] = ((unsigned long long)Kstar << 21) |
                   (unsigned long long)(0x1FFFFFu ^ (levtag | equ[t]));
  } else {
    if (tid == 0) sh_cnt = 0;
    __syncthreads();
    for (int i = tid; i < n; i += 1024) {
      float v = s[i];
      if (v > SCORE_THR) {
        unsigned slot = atomicAdd(&sh_cnt, 1u);
        out[slot] = ((unsigned long long)__float_as_uint(v) << 21) |
                    (unsigned long long)(0x1FFFFFu ^ (levtag | (unsigned)i));
      }
    }
    __syncthreads();
    unsigned need = k - c;
    unsigned base = 0;
    for (int start = 0; start < n && base < need; start += 1024) {
      int i = start + tid;
      unsigned pred = (i < n && !(s[i] > SCORE_THR)) ? 1u : 0u;
      scanbuf[tid] = pred;
      __syncthreads();
      for (int off = 1; off < 1024; off <<= 1) {
        unsigned add = (tid >= off) ? scanbuf[tid - off] : 0u;
        unsigned v = scanbuf[tid];
        __syncthreads();
        scanbuf[tid] = v + add;
        __syncthreads();
      }
      unsigned incl = scanbuf[tid];
      unsigned total = scanbuf[1023];
      unsigned excl = incl - pred;
      if (pred && (base + excl) < need)
        out[c + base + excl] =
            (unsigned long long)(0x1FFFFFu ^ (levtag | (unsigned)i));
      __syncthreads();
      base += total;
    }
  }
}

// ---------------- K3: per-image register-bitonic sort + decode -------------------
__device__ __forceinline__ unsigned physl(unsigned w) { return w ^ ((w >> 4) & 7u); }

__device__ __forceinline__ unsigned long long shfl64_xor(unsigned long long x, int m) {
  unsigned lo = (unsigned)x, hi = (unsigned)(x >> 32);
  lo = (unsigned)__shfl_xor((int)lo, m);
  hi = (unsigned)__shfl_xor((int)hi, m);
  return ((unsigned long long)hi << 32) | lo;
}

__global__ __launch_bounds__(1024) void k_sortdec(
    const unsigned long long* __restrict__ selkeys,
    const float* __restrict__ g0, const float* __restrict__ g1,
    const float* __restrict__ g2, const float* __restrict__ g3,
    const float* __restrict__ g4, const float* __restrict__ g5,
    float* __restrict__ boxes, float* __restrict__ oscore,
    int* __restrict__ olabel, int* __restrict__ ovalid,
    int* __restrict__ okeep, float* __restrict__ obmax)
{
  int b = blockIdx.x;
  int tid = threadIdx.x;
  __shared__ unsigned long long lds[8192];
  __shared__ double ba[6][6][4];
  __shared__ float red[1024];

  unsigned long long key[8];
  #pragma unroll
  for (int j = 0; j < 8; ++j) {
    int i = tid * 8 + j;
    key[j] = (i < KTOT) ? selkeys[(size_t)b * KTOT + i] : 0ull;
  }

  // bitonic sort (descending), 8 keys/thread
  for (unsigned sz = 2; sz <= 8192; sz <<= 1) {
    for (unsigned st = sz >> 1; st; st >>= 1) {
      if (st >= 512) {
        #pragma unroll
        for (int j = 0; j < 8; ++j) lds[physl(tid * 8 + j)] = key[j];
        __syncthreads();
        #pragma unroll
        for (int j = 0; j < 8; ++j) {
          unsigned v = tid * 8 + j;
          unsigned long long partner = lds[physl(v ^ st)];
          bool lower = ((v & st) == 0);
          unsigned long long lo_v = lower ? key[j] : partner;
          unsigned long long hi_v = lower ? partner : key[j];
          unsigned li = lower ? v : (v ^ st);
          bool up = ((li & sz) == 0);
          bool sw = ((lo_v < hi_v) == up);
          key[j] = sw ? (lower ? hi_v : lo_v) : key[j];
        }
        __syncthreads();
      } else if (st >= 8) {
        int m = (int)(st >> 3);
        #pragma unroll
        for (int j = 0; j < 8; ++j) {
          unsigned v = tid * 8 + j;
          unsigned long long partner = shfl64_xor(key[j], m);
          bool lower = ((v & st) == 0);
          unsigned long long lo_v = lower ? key[j] : partner;
          unsigned long long hi_v = lower ? partner : key[j];
          unsigned li = lower ? v : (v ^ st);
          bool up = ((li & sz) == 0);
          bool sw = ((lo_v < hi_v) == up);
          key[j] = sw ? (lower ? hi_v : lo_v) : key[j];
        }
      } else {
        unsigned vb = (unsigned)(tid * 8);
        #define CE(a, bb) { \
          unsigned v0 = vb + (a); \
          bool up = ((v0 & sz) == 0); \
          unsigned long long A = key[a], B = key[bb]; \
          if ((A < B) == up) { key[a] = B; key[bb] = A; } }
        if (st == 4)      { CE(0,4) CE(1,5) CE(2,6) CE(3,7) }
        else if (st == 2) { CE(0,2) CE(1,3) CE(4,6) CE(5,7) }
        else              { CE(0,1) CE(2,3) CE(4,5) CE(6,7) }
        #undef CE
      }
    }
  }
  #pragma unroll
  for (int j = 0; j < 8; ++j) lds[physl(tid * 8 + j)] = key[j];
  if (tid < 36) {  // base anchors in f64, matching numpy
    int lev = tid / 6, a = tid % 6;
    double base = (double)cMIN[lev];
    double scl = (a == 1) ? sqrt((double)cMAX[lev] / (double)cMIN[lev]) : 1.0;
    double hr = sqrt(cRATIO[a]);
    double wr = 1.0 / hr;
    double wsz = base * scl * wr;
    double hsz = base * scl * hr;
    double cc = (double)cSTRIDE[lev] / 2.0;
    ba[lev][a][0] = cc - 0.5 * wsz;
    ba[lev][a][1] = cc - 0.5 * hsz;
    ba[lev][a][2] = cc + 0.5 * wsz;
    ba[lev][a][3] = cc + 0.5 * hsz;
  }
  __syncthreads();

  float lmax = 0.f;
  for (int p = tid; p < KTOT; p += 1024) {
    unsigned long long k2 = lds[physl((unsigned)p)];
    unsigned tag = 0x1FFFFFu ^ (unsigned)(k2 & 0x1FFFFFull);
    int lev = tag >> 18;
    int fi = tag & 0x3FFFF;
    unsigned vb2 = (unsigned)(k2 >> 21);
    int valid = (vb2 != 0u);
    float score = valid ? __uint_as_float(vb2) : 0.f;
    int label = fi % 80;
    int arow = fi / 80;
    int a = arow % 6, cell = arow / 6;
    int f = cFEAT[lev], ff = f * f;
    int x = cell % f, y = cell / f;
    const float* gb = (lev==0)?g0:(lev==1)?g1:(lev==2)?g2:(lev==3)?g3:(lev==4)?g4:g5;
    const float* pb = gb + (size_t)(b * 24 + a * 4) * ff + y * f + x;
    float d0 = pb[0] * 0.1f, d1 = pb[ff] * 0.1f;
    float d2 = pb[2 * ff] * 0.2f, d3 = pb[3 * ff] * 0.2f;
    const float MR = (float)4.135166556742356;
    d2 = fminf(fmaxf(d2, -MR), MR);
    d3 = fminf(fmaxf(d3, -MR), MR);
    double shx = (double)(x * cSTRIDE[lev]);
    double shy = (double)(y * cSTRIDE[lev]);
    float p0 = (float)(ba[lev][a][0] + shx);
    float p1 = (float)(ba[lev][a][1] + shy);
    float p2 = (float)(ba[lev][a][2] + shx);
    float p3 = (float)(ba[lev][a][3] + shy);
    float pxc = (p0 + p2) * 0.5f, pyc = (p1 + p3) * 0.5f;
    float pw = p2 - p0, ph = p3 - p1;
    float gx = pxc + pw * d0, gy = pyc + ph * d1;
    float gw = pw * expf(d2), gh = ph * expf(d3);
    float x1 = gx - 0.5f * gw, y1 = gy - 0.5f * gh;
    float x2 = gx + 0.5f * gw, y2 = gy + 0.5f * gh;
    x1 = fminf(fmaxf(x1, 0.f), 320.f);
    y1 = fminf(fmaxf(y1, 0.f), 320.f);
    x2 = fminf(fmaxf(x2, 0.f), 320.f);
    y2 = fminf(fmaxf(y2, 0.f), 320.f);
    size_t o = (size_t)(b * KTOT + p);
    boxes[o * 4 + 0] = x1; boxes[o * 4 + 1] = y1;
    boxes[o * 4 + 2] = x2; boxes[o * 4 + 3] = y2;
    oscore[o] = score; olabel[o] = label; ovalid[o] = valid; okeep[o] = 0;
    lmax = fmaxf(lmax, fmaxf(fmaxf(x1, y1), fmaxf(x2, y2)));
  }
  red[tid] = lmax;
  __syncthreads();
  for (int s2 = 512; s2; s2 >>= 1) {
    if (tid < s2) red[tid] = fmaxf(red[tid], red[tid + s2]);
    __syncthreads();
  }
  if (tid == 0) obmax[b] = red[0];
}

// ---------------- K4: per (image,class) greedy NMS, one wave each -----------------
__global__ __launch_bounds__(256) void k_nms(
    const float* __restrict__ boxes, const int* __restrict__ olabel,
    const int* __restrict__ ovalid, int* __restrict__ okeep,
    const float* __restrict__ obmax)
{
  int wv = blockIdx.x * 4 + (threadIdx.x >> 6);
  int lane = threadIdx.x & 63;
  int b = wv / 80, cls = wv % 80;
  __shared__ unsigned short lists[4][512];
  unsigned short* list = lists[threadIdx.x >> 6];
  const int* lab = olabel + b * KTOT;
  const int* val = ovalid + b * KTOT;
  float ofs = (float)cls * (obmax[b] + 1.0f);
  int nlist = 0;
  for (int base = 0; base < KTOT; base += 64) {
    int i = base + lane;
    bool pred = (i < KTOT) && (val[i] != 0) && (lab[i] == cls);
    unsigned long long ball = __ballot(pred);
    if (pred) {
      int pos = nlist + (int)__popcll(ball & ((1ull << lane) - 1ull));
      if (pos < 512) list[pos] = (unsigned short)i;
    }
    nlist += (int)__popcll(ball);
  }
  if (nlist > 512) nlist = 512;
  int S = (nlist + 63) >> 6;
  float x1[8], y1[8], x2[8], y2[8], ar[8];
  int alive[8];
  #pragma unroll
  for (int s = 0; s < 8; ++s) {
    x1[s] = y1[s] = x2[s] = y2[s] = ar[s] = 0.f; alive[s] = 0;
    int idx = s * 64 + lane;
    if (s < S && idx < nlist) {
      const float* bp = boxes + (size_t)(b * KTOT + list[idx]) * 4;
      x1[s] = bp[0] + ofs; y1[s] = bp[1] + ofs;
      x2[s] = bp[2] + ofs; y2[s] = bp[3] + ofs;
      ar[s] = (x2[s] - x1[s]) * (y2[s] - y1[s]);
      alive[s] = 1;
    }
  }
  #pragma unroll
  for (int s = 0; s < 8; ++s) {
    if (s < S) {
      int lim = nlist - s * 64; if (lim > 64) lim = 64;
      for (int li = 0; li < lim; ++li) {
        int i = s * 64 + li;
        int av = __shfl(alive[s], li);
        if (av) {
          float bx1 = __shfl(x1[s], li), by1 = __shfl(y1[s], li);
          float bx2 = __shfl(x2[s], li), by2 = __shfl(y2[s], li);
          float bar = __shfl(ar[s], li);
          #pragma unroll
          for (int t = 0; t < 8; ++t) {
            if (t < S) {
              float ix1 = fmaxf(x1[t], bx1), iy1 = fmaxf(y1[t], by1);
              float ix2 = fminf(x2[t], bx2), iy2 = fminf(y2[t], by2);
              float iw = fmaxf(ix2 - ix1, 0.f), ih = fmaxf(iy2 - iy1, 0.f);
              float inter = iw * ih;
              float iou = inter / (ar[t] + bar - inter);
              if ((iou > IOU_THR) && ((t * 64 + lane) > i)) alive[t] = 0;
            }
          }
        }
      }
    }
  }
  #pragma unroll
  for (int s = 0; s < 8; ++s) {
    int idx = s * 64 + lane;
    if (s < S && idx < nlist) okeep[b * KTOT + list[idx]] = alive[s];
  }
}

// ---------------- K5: final outputs ----------------------------------------------
__global__ __launch_bounds__(256) void k_write(
    const float* __restrict__ boxes, const float* __restrict__ oscore,
    const int* __restrict__ olabel, const int* __restrict__ okeep,
    float* __restrict__ out)
{
  int t = blockIdx.x * 256 + threadIdx.x;
  if (t >= NB * KTOT) return;
  float kf = okeep[t] ? 1.f : 0.f;
  const float* bp = boxes + (size_t)t * 4;
  float* det = out + (size_t)t * 5;
  det[0] = bp[0] * kf; det[1] = bp[1] * kf;
  det[2] = bp[2] * kf; det[3] = bp[3] * kf;
  det[4] = oscore[t] * kf;
  out[(size_t)NB * KTOT * 5 + t] = (float)olabel[t];
  out[(size_t)NB * KTOT * 6 + t] = kf;
}

extern "C" void kernel_launch(void* const* d_in, const int* in_sizes, int n_in,
                              void* d_out, int out_size, void* d_ws, size_t ws_size,
                              hipStream_t stream) {
  (void)in_sizes; (void)n_in; (void)out_size; (void)ws_size;
  const float* cls[6]; const float* bbx[6];
  for (int i = 0; i < 6; ++i) {
    cls[i] = (const float*)d_in[2 * i];
    bbx[i] = (const float*)d_in[2 * i + 1];
  }
  char* ws = (char*)d_ws;
  float* scores = (float*)ws;                                         // 4,139,520
  unsigned long long* selkeys = (unsigned long long*)(ws + 4139520);  // 175,360
  float* boxes  = (float*)(ws + 4314880);                             // 350,720
  float* oscore = (float*)(ws + 4665600);
  int*   olabel = (int*)(ws + 4753280);
  int*   ovalid = (int*)(ws + 4840960);
  int*   okeep  = (int*)(ws + 4928640);
  float* obmax  = (float*)(ws + 5016320);
  unsigned* ghist = (unsigned*)(ws + 5016576);                        // 24*8192*4 = 786,432
  unsigned* ctrl  = (unsigned*)(ws + 5803008);                        // 24*8*4 = 768
  unsigned long long* eqbuf = (unsigned long long*)(ws + 5803776);    // 24*4096*8 = 786,432

  hipMemsetAsync(ws + 5016576, 0, 786432 + 768, stream);
  k_softmax<<<3234, 256, 0, stream>>>(cls[0], cls[1], cls[2], cls[3], cls[4], cls[5],
                                      scores, ghist);
  k_cutoff<<<24, 1024, 0, stream>>>(ghist, ctrl);
  k_emit<<<(NB * PER_IMG + 255) / 256, 256, 0, stream>>>(scores, ctrl, selkeys, eqbuf);
  k_finalize<<<24, 1024, 0, stream>>>(scores, ctrl, selkeys, eqbuf);
  k_sortdec<<<4, 1024, 0, stream>>>(selkeys, bbx[0], bbx[1], bbx[2], bbx[3], bbx[4], bbx[5],
                                    boxes, oscore, olabel, ovalid, okeep, obmax);
  k_nms<<<80, 256, 0, stream>>>(boxes, olabel, ovalid, okeep, obmax);
  k_write<<<(NB * KTOT + 255) / 256, 256, 0, stream>>>(boxes, oscore, olabel, okeep, (float*)d_out);
}

// Round 3
// 214.825 us; speedup vs baseline: 2.4593x; 1.3012x over previous
//
#include <hip/hip_runtime.h>
#include <stdint.h>

#define NB 4
#define KTOT 5480
#define PER_IMG 258720
#define SCORE_THR 0.02f
#define IOU_THR 0.45f
#define REL_BASE 0x3CA3D70Bu   // smallest float bits > 0.02f

__constant__ int cFEAT[6]    = {20,10,5,3,2,1};
__constant__ int cSTRIDE[6]  = {16,32,64,107,160,320};
__constant__ int cMIN[6]     = {48,100,150,202,253,304};
__constant__ int cMAX[6]     = {100,150,202,253,304,320};
__constant__ int cNFLAT[6]   = {192000,48000,12000,4320,1920,480};
__constant__ int cFLATOFF[6] = {0,192000,240000,252000,256320,258240};
__constant__ int cKSEL[6]    = {1000,1000,1000,1000,1000,480};
__constant__ int cKOFF[6]    = {0,1000,2000,3000,4000,5000};
__constant__ int cROWCUM[7]  = {0,2400,3000,3150,3204,3228,3234};
__constant__ double cRATIO[6] = {1.0,1.0,0.5,2.0,1.0/3.0,3.0};

__device__ __forceinline__ unsigned long long mk_key(unsigned kb, int lev, unsigned idx) {
  return ((unsigned long long)kb << 21) |
         (unsigned long long)(0x1FFFFFu ^ (((unsigned)lev << 18) | idx));
}

// ---------------- K1: softmax over 81 classes + fused 13-bit histogram -----------
__global__ __launch_bounds__(256) void k_softmax(
    const float* __restrict__ c0, const float* __restrict__ c1,
    const float* __restrict__ c2, const float* __restrict__ c3,
    const float* __restrict__ c4, const float* __restrict__ c5,
    float* __restrict__ scores, unsigned* __restrict__ ghist)
{
  int w = (int)((blockIdx.x * blockDim.x + threadIdx.x) >> 6);
  int lane = threadIdx.x & 63;
  if (w >= NB * 3234) return;
  int b = w / 3234, rg = w % 3234;
  int lev = 0;
  #pragma unroll
  for (int l = 0; l < 5; ++l) lev += (rg >= cROWCUM[l + 1]);
  int row = rg - cROWCUM[lev];
  const float* cls = (lev==0)?c0:(lev==1)?c1:(lev==2)?c2:(lev==3)?c3:(lev==4)?c4:c5;
  int f = cFEAT[lev], ff = f * f;
  int a = row % 6, cell = row / 6;
  int x = cell % f, y = cell / f;
  const float* pc = cls + (size_t)(b * 486 + a * 81) * ff + y * f + x;
  float v1 = pc[lane * ff];
  float v2 = (lane <= 16) ? pc[(lane + 64) * ff] : __uint_as_float(0xff800000u);
  float mx = fmaxf(v1, v2);
  #pragma unroll
  for (int m = 32; m; m >>= 1) mx = fmaxf(mx, __shfl_xor(mx, m));
  float e1 = expf(v1 - mx);
  float e2 = (lane <= 16) ? expf(v2 - mx) : 0.f;
  float sm = e1 + e2;
  #pragma unroll
  for (int m = 32; m; m >>= 1) sm += __shfl_xor(sm, m);
  float* out = scores + (size_t)b * PER_IMG + cFLATOFF[lev] + row * 80;
  unsigned* h = ghist + (size_t)(b * 6 + lev) * 8192;
  float p1 = e1 / sm;
  out[lane] = (p1 > SCORE_THR) ? p1 : -1.f;
  if (p1 > SCORE_THR)
    atomicAdd(&h[(__float_as_uint(p1) - REL_BASE) >> 13], 1u);
  if (lane < 16) {
    float p2 = e2 / sm;
    out[lane + 64] = (p2 > SCORE_THR) ? p2 : -1.f;
    if (p2 > SCORE_THR)
      atomicAdd(&h[(__float_as_uint(p2) - REL_BASE) >> 13], 1u);
  }
}

// ---------------- K2: fused per-(img,level) exact top-k selection ----------------
// One block per task; all slot counters in LDS (no global atomic contention).
__global__ __launch_bounds__(1024) void k_select(
    const float* __restrict__ scores, const unsigned* __restrict__ ghist,
    unsigned long long* __restrict__ selkeys)
{
  int task = blockIdx.x;
  int b = task / 6, lev = task % 6;
  int tid = threadIdx.x;
  int n = cNFLAT[lev];
  unsigned k = (unsigned)cKSEL[lev];
  const float* s = scores + (size_t)b * PER_IMG + cFLATOFF[lev];
  unsigned long long* out = selkeys + (size_t)b * KTOT + cKOFF[lev];
  unsigned levtag = (unsigned)lev << 18;

  if (lev == 5) {  // keep all (k == n)
    for (int i = tid; i < n; i += 1024) {
      float v = s[i];
      unsigned kb = (v > SCORE_THR) ? __float_as_uint(v) : 0u;
      out[i] = mk_key(kb, lev, (unsigned)i);
    }
    return;
  }

  __shared__ unsigned sc[1024];            // scan buffer (also hist/scan alias in slowpaths)
  __shared__ unsigned long long eqb[4096]; // cutoff-bin tie buffer
  __shared__ unsigned sh_cnt, sh_eq, sh_b1, sh_byte, sh_r;

  // ---- cutoff-bin search from precomputed histogram ----
  const unsigned* h = ghist + (size_t)task * 8192;
  unsigned loc[8];
  unsigned ssum = 0;
  #pragma unroll
  for (int j = 0; j < 8; ++j) { loc[j] = h[tid * 8 + j]; ssum += loc[j]; }
  sc[tid] = ssum;
  __syncthreads();
  for (int off = 1; off < 1024; off <<= 1) {   // suffix-inclusive sum
    unsigned cur = sc[tid];
    unsigned add = (tid + off < 1024) ? sc[tid + off] : 0u;
    __syncthreads();
    sc[tid] = cur + add;
    __syncthreads();
  }
  unsigned c = sc[0];

  if (c >= k) {
    // ---- mode 0: find bin b1 containing the k-th value ----
    unsigned above = (tid == 1023) ? 0u : sc[tid + 1];
    unsigned run = above;
    #pragma unroll
    for (int j = 7; j >= 0; --j) {
      unsigned hj = loc[j];
      if (run < k && run + hj >= k) sh_b1 = (unsigned)(tid * 8 + j);
      run += hj;
    }
    if (tid == 0) { sh_cnt = 0; sh_eq = 0; }
    __syncthreads();
    unsigned b1 = sh_b1;
    unsigned base_lo = REL_BASE + (b1 << 13);
    unsigned base_hi = base_lo + 8192u;

    // ---- single streaming pass, vectorized ----
    const float4* s4 = (const float4*)s;
    int n4 = n >> 2;
    #pragma unroll 4
    for (int i0 = tid; i0 < n4; i0 += 1024) {
      float4 vv = s4[i0];
      #pragma unroll
      for (int e = 0; e < 4; ++e) {
        float v = (e == 0) ? vv.x : (e == 1) ? vv.y : (e == 2) ? vv.z : vv.w;
        if (v > SCORE_THR) {
          unsigned kb = __float_as_uint(v);
          unsigned idx = (unsigned)(i0 * 4 + e);
          if (kb >= base_hi) {
            unsigned slot = atomicAdd(&sh_cnt, 1u);
            out[slot] = mk_key(kb, lev, idx);
          } else if (kb >= base_lo) {
            unsigned p = atomicAdd(&sh_eq, 1u);
            if (p < 4096u) eqb[p] = mk_key(kb, lev, idx);
          }
        }
      }
    }
    __syncthreads();
    unsigned cnt = sh_cnt;
    unsigned e = sh_eq;
    unsigned need = k - cnt;
    if (e <= 4096u) {
      if (e == need) {
        for (unsigned t = tid; t < need; t += 1024) out[cnt + t] = eqb[t];
      } else {
        unsigned P = 1; while (P < e) P <<= 1;
        for (unsigned t = tid; t < P; t += 1024) if (t >= e) eqb[t] = 0ull;
        __syncthreads();
        for (unsigned sz = 2; sz <= P; sz <<= 1)
          for (unsigned st = sz >> 1; st; st >>= 1) {
            for (unsigned w = tid; w < P / 2; w += 1024) {
              unsigned i = ((w & ~(st - 1)) << 1) | (w & (st - 1));
              unsigned l = i | st;
              bool up = ((i & sz) == 0);
              unsigned long long A = eqb[i], B = eqb[l];
              if ((A < B) == up) { eqb[i] = B; eqb[l] = A; }  // descending
            }
            __syncthreads();
          }
        for (unsigned t = tid; t < need; t += 1024) out[cnt + t] = eqb[t];
      }
      return;
    }

    // ---- pathological eq overflow: exact byte-radix slowpath ----
    unsigned* hist = sc;               // alias (first 256)
    unsigned* equ = (unsigned*)eqb;    // u32 index buffer, cap 4096
    unsigned prefix = 0, r = k;
    for (int pass = 3; pass >= 0; --pass) {
      int shift = pass * 8;
      for (int i = tid; i < 256; i += 1024) hist[i] = 0;
      __syncthreads();
      for (int i = tid; i < n; i += 1024) {
        float v = s[i];
        unsigned kb = (v > SCORE_THR) ? __float_as_uint(v) : 0u;
        bool match = (pass == 3) || (((kb ^ prefix) >> (shift + 8)) == 0u);
        if (match) atomicAdd(&hist[(kb >> shift) & 255u], 1u);
      }
      __syncthreads();
      if (tid == 0) {
        unsigned cum = 0, byte = 0, rr = r;
        for (int bb = 255; bb >= 0; --bb) {
          unsigned hh = hist[bb];
          if (cum + hh >= r) { byte = (unsigned)bb; rr = r - cum; break; }
          cum += hh;
        }
        sh_byte = byte; sh_r = rr;
      }
      __syncthreads();
      prefix |= (sh_byte << shift);
      r = sh_r;
      __syncthreads();
    }
    unsigned Kstar = prefix;
    if (tid == 0) { sh_cnt = 0; sh_eq = 0; }
    __syncthreads();
    for (int i = tid; i < n; i += 1024) {
      float v = s[i];
      unsigned kb = (v > SCORE_THR) ? __float_as_uint(v) : 0u;
      if (kb > Kstar) {
        unsigned slot = atomicAdd(&sh_cnt, 1u);
        out[slot] = mk_key(kb, lev, (unsigned)i);
      } else if (kb == Kstar) {
        unsigned es = atomicAdd(&sh_eq, 1u);
        if (es < 4096u) equ[es] = (unsigned)i;
      }
    }
    __syncthreads();
    unsigned m = sh_cnt;
    unsigned e2 = (sh_eq < 4096u) ? sh_eq : 4096u;
    unsigned need2 = k - m;
    if (e2 > need2) {
      unsigned P = 1; while (P < e2) P <<= 1;
      for (unsigned t = tid; t < P; t += 1024) if (t >= e2) equ[t] = 0xFFFFFFFFu;
      __syncthreads();
      for (unsigned sz = 2; sz <= P; sz <<= 1)
        for (unsigned st = sz >> 1; st; st >>= 1) {
          for (unsigned w = tid; w < P / 2; w += 1024) {
            unsigned i = ((w & ~(st - 1)) << 1) | (w & (st - 1));
            unsigned l = i | st;
            bool up = ((i & sz) == 0);
            unsigned A = equ[i], B = equ[l];
            if ((A > B) == up) { equ[i] = B; equ[l] = A; }  // ascending
          }
          __syncthreads();
        }
    }
    __syncthreads();
    for (unsigned t = tid; t < need2; t += 1024)
      out[m + t] = ((unsigned long long)Kstar << 21) |
                   (unsigned long long)(0x1FFFFFu ^ (levtag | equ[t]));
    return;
  }

  // ---- mode 1: fewer candidates than k — all candidates + ordered fillers ----
  if (tid == 0) sh_cnt = 0;
  __syncthreads();
  {
    const float4* s4 = (const float4*)s;
    int n4 = n >> 2;
    #pragma unroll 4
    for (int i0 = tid; i0 < n4; i0 += 1024) {
      float4 vv = s4[i0];
      #pragma unroll
      for (int e = 0; e < 4; ++e) {
        float v = (e == 0) ? vv.x : (e == 1) ? vv.y : (e == 2) ? vv.z : vv.w;
        if (v > SCORE_THR) {
          unsigned slot = atomicAdd(&sh_cnt, 1u);
          out[slot] = mk_key(__float_as_uint(v), lev, (unsigned)(i0 * 4 + e));
        }
      }
    }
  }
  __syncthreads();
  unsigned need = k - c;
  unsigned base = 0;
  unsigned* scanbuf = sc;
  for (int start = 0; start < n && base < need; start += 1024) {
    int i = start + tid;
    unsigned pred = (i < n && !(s[i] > SCORE_THR)) ? 1u : 0u;
    scanbuf[tid] = pred;
    __syncthreads();
    for (int off = 1; off < 1024; off <<= 1) {
      unsigned add = (tid >= off) ? scanbuf[tid - off] : 0u;
      unsigned v = scanbuf[tid];
      __syncthreads();
      scanbuf[tid] = v + add;
      __syncthreads();
    }
    unsigned incl = scanbuf[tid];
    unsigned total = scanbuf[1023];
    unsigned excl = incl - pred;
    if (pred && (base + excl) < need)
      out[c + base + excl] =
          (unsigned long long)(0x1FFFFFu ^ (levtag | (unsigned)i));
    __syncthreads();
    base += total;
  }
}

// ---------------- K3: per-image register-bitonic sort + decode -------------------
__device__ __forceinline__ unsigned physl(unsigned w) { return w ^ ((w >> 4) & 7u); }

__device__ __forceinline__ unsigned long long shfl64_xor(unsigned long long x, int m) {
  unsigned lo = (unsigned)x, hi = (unsigned)(x >> 32);
  lo = (unsigned)__shfl_xor((int)lo, m);
  hi = (unsigned)__shfl_xor((int)hi, m);
  return ((unsigned long long)hi << 32) | lo;
}

__global__ __launch_bounds__(1024) void k_sortdec(
    const unsigned long long* __restrict__ selkeys,
    const float* __restrict__ g0, const float* __restrict__ g1,
    const float* __restrict__ g2, const float* __restrict__ g3,
    const float* __restrict__ g4, const float* __restrict__ g5,
    float* __restrict__ boxes, float* __restrict__ oscore,
    int* __restrict__ olabel, int* __restrict__ ovalid,
    int* __restrict__ okeep, float* __restrict__ obmax)
{
  int b = blockIdx.x;
  int tid = threadIdx.x;
  __shared__ unsigned long long lds[8192];
  __shared__ double ba[6][6][4];
  __shared__ float red[1024];

  unsigned long long key[8];
  #pragma unroll
  for (int j = 0; j < 8; ++j) {
    int i = tid * 8 + j;
    key[j] = (i < KTOT) ? selkeys[(size_t)b * KTOT + i] : 0ull;
  }

  for (unsigned sz = 2; sz <= 8192; sz <<= 1) {
    for (unsigned st = sz >> 1; st; st >>= 1) {
      if (st >= 512) {
        #pragma unroll
        for (int j = 0; j < 8; ++j) lds[physl(tid * 8 + j)] = key[j];
        __syncthreads();
        #pragma unroll
        for (int j = 0; j < 8; ++j) {
          unsigned v = tid * 8 + j;
          unsigned long long partner = lds[physl(v ^ st)];
          bool lower = ((v & st) == 0);
          unsigned long long lo_v = lower ? key[j] : partner;
          unsigned long long hi_v = lower ? partner : key[j];
          unsigned li = lower ? v : (v ^ st);
          bool up = ((li & sz) == 0);
          bool sw = ((lo_v < hi_v) == up);
          key[j] = sw ? (lower ? hi_v : lo_v) : key[j];
        }
        __syncthreads();
      } else if (st >= 8) {
        int m = (int)(st >> 3);
        #pragma unroll
        for (int j = 0; j < 8; ++j) {
          unsigned v = tid * 8 + j;
          unsigned long long partner = shfl64_xor(key[j], m);
          bool lower = ((v & st) == 0);
          unsigned long long lo_v = lower ? key[j] : partner;
          unsigned long long hi_v = lower ? partner : key[j];
          unsigned li = lower ? v : (v ^ st);
          bool up = ((li & sz) == 0);
          bool sw = ((lo_v < hi_v) == up);
          key[j] = sw ? (lower ? hi_v : lo_v) : key[j];
        }
      } else {
        unsigned vb = (unsigned)(tid * 8);
        #define CE(a, bb) { \
          unsigned v0 = vb + (a); \
          bool up = ((v0 & sz) == 0); \
          unsigned long long A = key[a], B = key[bb]; \
          if ((A < B) == up) { key[a] = B; key[bb] = A; } }
        if (st == 4)      { CE(0,4) CE(1,5) CE(2,6) CE(3,7) }
        else if (st == 2) { CE(0,2) CE(1,3) CE(4,6) CE(5,7) }
        else              { CE(0,1) CE(2,3) CE(4,5) CE(6,7) }
        #undef CE
      }
    }
  }
  #pragma unroll
  for (int j = 0; j < 8; ++j) lds[physl(tid * 8 + j)] = key[j];
  if (tid < 36) {
    int lev = tid / 6, a = tid % 6;
    double base = (double)cMIN[lev];
    double scl = (a == 1) ? sqrt((double)cMAX[lev] / (double)cMIN[lev]) : 1.0;
    double hr = sqrt(cRATIO[a]);
    double wr = 1.0 / hr;
    double wsz = base * scl * wr;
    double hsz = base * scl * hr;
    double cc = (double)cSTRIDE[lev] / 2.0;
    ba[lev][a][0] = cc - 0.5 * wsz;
    ba[lev][a][1] = cc - 0.5 * hsz;
    ba[lev][a][2] = cc + 0.5 * wsz;
    ba[lev][a][3] = cc + 0.5 * hsz;
  }
  __syncthreads();

  float lmax = 0.f;
  for (int p = tid; p < KTOT; p += 1024) {
    unsigned long long k2 = lds[physl((unsigned)p)];
    unsigned tag = 0x1FFFFFu ^ (unsigned)(k2 & 0x1FFFFFull);
    int lev = tag >> 18;
    int fi = tag & 0x3FFFF;
    unsigned vb2 = (unsigned)(k2 >> 21);
    int valid = (vb2 != 0u);
    float score = valid ? __uint_as_float(vb2) : 0.f;
    int label = fi % 80;
    int arow = fi / 80;
    int a = arow % 6, cell = arow / 6;
    int f = cFEAT[lev], ff = f * f;
    int x = cell % f, y = cell / f;
    const float* gb = (lev==0)?g0:(lev==1)?g1:(lev==2)?g2:(lev==3)?g3:(lev==4)?g4:g5;
    const float* pb = gb + (size_t)(b * 24 + a * 4) * ff + y * f + x;
    float d0 = pb[0] * 0.1f, d1 = pb[ff] * 0.1f;
    float d2 = pb[2 * ff] * 0.2f, d3 = pb[3 * ff] * 0.2f;
    const float MR = (float)4.135166556742356;
    d2 = fminf(fmaxf(d2, -MR), MR);
    d3 = fminf(fmaxf(d3, -MR), MR);
    double shx = (double)(x * cSTRIDE[lev]);
    double shy = (double)(y * cSTRIDE[lev]);
    float p0 = (float)(ba[lev][a][0] + shx);
    float p1 = (float)(ba[lev][a][1] + shy);
    float p2 = (float)(ba[lev][a][2] + shx);
    float p3 = (float)(ba[lev][a][3] + shy);
    float pxc = (p0 + p2) * 0.5f, pyc = (p1 + p3) * 0.5f;
    float pw = p2 - p0, ph = p3 - p1;
    float gx = pxc + pw * d0, gy = pyc + ph * d1;
    float gw = pw * expf(d2), gh = ph * expf(d3);
    float x1 = gx - 0.5f * gw, y1 = gy - 0.5f * gh;
    float x2 = gx + 0.5f * gw, y2 = gy + 0.5f * gh;
    x1 = fminf(fmaxf(x1, 0.f), 320.f);
    y1 = fminf(fmaxf(y1, 0.f), 320.f);
    x2 = fminf(fmaxf(x2, 0.f), 320.f);
    y2 = fminf(fmaxf(y2, 0.f), 320.f);
    size_t o = (size_t)(b * KTOT + p);
    boxes[o * 4 + 0] = x1; boxes[o * 4 + 1] = y1;
    boxes[o * 4 + 2] = x2; boxes[o * 4 + 3] = y2;
    oscore[o] = score; olabel[o] = label; ovalid[o] = valid; okeep[o] = 0;
    lmax = fmaxf(lmax, fmaxf(fmaxf(x1, y1), fmaxf(x2, y2)));
  }
  red[tid] = lmax;
  __syncthreads();
  for (int s2 = 512; s2; s2 >>= 1) {
    if (tid < s2) red[tid] = fmaxf(red[tid], red[tid + s2]);
    __syncthreads();
  }
  if (tid == 0) obmax[b] = red[0];
}

// ---------------- K4: per (image,class) greedy NMS, one wave each -----------------
__global__ __launch_bounds__(256) void k_nms(
    const float* __restrict__ boxes, const int* __restrict__ olabel,
    const int* __restrict__ ovalid, int* __restrict__ okeep,
    const float* __restrict__ obmax)
{
  int wv = blockIdx.x * 4 + (threadIdx.x >> 6);
  int lane = threadIdx.x & 63;
  int b = wv / 80, cls = wv % 80;
  __shared__ unsigned short lists[4][512];
  unsigned short* list = lists[threadIdx.x >> 6];
  const int* lab = olabel + b * KTOT;
  const int* val = ovalid + b * KTOT;
  float ofs = (float)cls * (obmax[b] + 1.0f);
  int nlist = 0;
  for (int base = 0; base < KTOT; base += 64) {
    int i = base + lane;
    bool pred = (i < KTOT) && (val[i] != 0) && (lab[i] == cls);
    unsigned long long ball = __ballot(pred);
    if (pred) {
      int pos = nlist + (int)__popcll(ball & ((1ull << lane) - 1ull));
      if (pos < 512) list[pos] = (unsigned short)i;
    }
    nlist += (int)__popcll(ball);
  }
  if (nlist > 512) nlist = 512;
  int S = (nlist + 63) >> 6;
  float x1[8], y1[8], x2[8], y2[8], ar[8];
  int alive[8];
  #pragma unroll
  for (int s = 0; s < 8; ++s) {
    x1[s] = y1[s] = x2[s] = y2[s] = ar[s] = 0.f; alive[s] = 0;
    int idx = s * 64 + lane;
    if (s < S && idx < nlist) {
      const float* bp = boxes + (size_t)(b * KTOT + list[idx]) * 4;
      x1[s] = bp[0] + ofs; y1[s] = bp[1] + ofs;
      x2[s] = bp[2] + ofs; y2[s] = bp[3] + ofs;
      ar[s] = (x2[s] - x1[s]) * (y2[s] - y1[s]);
      alive[s] = 1;
    }
  }
  #pragma unroll
  for (int s = 0; s < 8; ++s) {
    if (s < S) {
      int lim = nlist - s * 64; if (lim > 64) lim = 64;
      for (int li = 0; li < lim; ++li) {
        int i = s * 64 + li;
        int av = __shfl(alive[s], li);
        if (av) {
          float bx1 = __shfl(x1[s], li), by1 = __shfl(y1[s], li);
          float bx2 = __shfl(x2[s], li), by2 = __shfl(y2[s], li);
          float bar = __shfl(ar[s], li);
          #pragma unroll
          for (int t = 0; t < 8; ++t) {
            if (t < S) {
              float ix1 = fmaxf(x1[t], bx1), iy1 = fmaxf(y1[t], by1);
              float ix2 = fminf(x2[t], bx2), iy2 = fminf(y2[t], by2);
              float iw = fmaxf(ix2 - ix1, 0.f), ih = fmaxf(iy2 - iy1, 0.f);
              float inter = iw * ih;
              float iou = inter / (ar[t] + bar - inter);
              if ((iou > IOU_THR) && ((t * 64 + lane) > i)) alive[t] = 0;
            }
          }
        }
      }
    }
  }
  #pragma unroll
  for (int s = 0; s < 8; ++s) {
    int idx = s * 64 + lane;
    if (s < S && idx < nlist) okeep[b * KTOT + list[idx]] = alive[s];
  }
}

// ---------------- K5: final outputs ----------------------------------------------
__global__ __launch_bounds__(256) void k_write(
    const float* __restrict__ boxes, const float* __restrict__ oscore,
    const int* __restrict__ olabel, const int* __restrict__ okeep,
    float* __restrict__ out)
{
  int t = blockIdx.x * 256 + threadIdx.x;
  if (t >= NB * KTOT) return;
  float kf = okeep[t] ? 1.f : 0.f;
  const float* bp = boxes + (size_t)t * 4;
  float* det = out + (size_t)t * 5;
  det[0] = bp[0] * kf; det[1] = bp[1] * kf;
  det[2] = bp[2] * kf; det[3] = bp[3] * kf;
  det[4] = oscore[t] * kf;
  out[(size_t)NB * KTOT * 5 + t] = (float)olabel[t];
  out[(size_t)NB * KTOT * 6 + t] = kf;
}

extern "C" void kernel_launch(void* const* d_in, const int* in_sizes, int n_in,
                              void* d_out, int out_size, void* d_ws, size_t ws_size,
                              hipStream_t stream) {
  (void)in_sizes; (void)n_in; (void)out_size; (void)ws_size;
  const float* cls[6]; const float* bbx[6];
  for (int i = 0; i < 6; ++i) {
    cls[i] = (const float*)d_in[2 * i];
    bbx[i] = (const float*)d_in[2 * i + 1];
  }
  char* ws = (char*)d_ws;
  float* scores = (float*)ws;                                         // 4,139,520
  unsigned long long* selkeys = (unsigned long long*)(ws + 4139520);  // 175,360
  float* boxes  = (float*)(ws + 4314880);                             // 350,720
  float* oscore = (float*)(ws + 4665600);
  int*   olabel = (int*)(ws + 4753280);
  int*   ovalid = (int*)(ws + 4840960);
  int*   okeep  = (int*)(ws + 4928640);
  float* obmax  = (float*)(ws + 5016320);
  unsigned* ghist = (unsigned*)(ws + 5016576);                        // 24*8192*4 = 786,432

  hipMemsetAsync(ws + 5016576, 0, 786432, stream);
  k_softmax<<<3234, 256, 0, stream>>>(cls[0], cls[1], cls[2], cls[3], cls[4], cls[5],
                                      scores, ghist);
  k_select<<<24, 1024, 0, stream>>>(scores, ghist, selkeys);
  k_sortdec<<<4, 1024, 0, stream>>>(selkeys, bbx[0], bbx[1], bbx[2], bbx[3], bbx[4], bbx[5],
                                    boxes, oscore, olabel, ovalid, okeep, obmax);
  k_nms<<<80, 256, 0, stream>>>(boxes, olabel, ovalid, okeep, obmax);
  k_write<<<(NB * KTOT + 255) / 256, 256, 0, stream>>>(boxes, oscore, olabel, okeep, (float*)d_out);
}